// Round 6
// baseline (157.052 us; speedup 1.0000x reference)
//
#include <hip/hip_runtime.h>
#include <hip/hip_bf16.h>

// Retention: out = (tril(alpha^(i-j)) * (QK^T/sqrt(d))) @ V, qkv = x@W + b
// Decay folded into operands: Q' = q*alpha^i/sqrt(d), K' = k*alpha^(-j)
// Shared GEMM core: 256x256 tile, BK=32, 4-deep LDS ring (128KB), 8 waves
// (128x64/wave, acc[8][4]), staging 3 K-tiles ahead via global_load_lds,
// ONE barrier + ONE counted vmcnt(8) per K-tile, 2 MFMA phases (16 each) with
// setprio. LDS: 2 rows/128B line, slot = ((r&1)*4+lg)^((r>>1)&7) swizzle
// applied on pre-swizzled global source + swizzled ds_read (dest stays linear).
//
// Race-freedom of the single-barrier ring:
//  - gate at end of tile t waits vmcnt(8): queue is [t+1,t+2,t+3] (12 loads)
//    -> oldest 4 (= tile t+1) complete. All waves gate before the barrier, so
//    after it tile t+1 is fully visible to the block.
//  - stage of tile t+3 (buffer (t+3)&3 = (t-1)&3) is issued after barrier t-1;
//    every wave finished its reads of tile t-1 (lgkm-complete before its MFMA)
//    before arriving at barrier t-1 -> no write-after-read race.
//  - wave skew is bounded by the per-tile barrier (max 1 tile) < 3-tile margin.

#define SEQ   1024
#define DIM   768
#define ND3   2304

typedef __attribute__((ext_vector_type(8))) short bf16x8;
typedef __attribute__((ext_vector_type(4))) float f32x4;

#define L2A     (-0.014499569695115089f)   // log2(0.99)
#define RSQRTD  (0.03608439182435161f)     // 1/sqrt(768)

__device__ __forceinline__ unsigned short f2bf(float x) {
  union { float f; unsigned u; } v; v.f = x;
  unsigned r = v.u + 0x7FFFu + ((v.u >> 16) & 1u);
  return (unsigned short)(r >> 16);
}

__device__ __forceinline__ void gload16(const void* g, void* l) {
  __builtin_amdgcn_global_load_lds(
      (const __attribute__((address_space(1))) void*)g,
      (__attribute__((address_space(3))) void*)l, 16, 0, 0);
}

// ---- core: acc[8][4] += A[256 x nt*32] @ B[256 x nt*32]^T (row-major, K contig)
// pA/pB: per-lane staging srcs = base + (tile_row0 + rloc)*ld + colo, where
//   c8 = (lane&7)^(lane>>3); rloc = (lane>>3)*2 + (c8>>2); colo = (c8&3)*8.
__device__ __forceinline__ void gemm256(
    const unsigned short* pA, const unsigned short* pB, int ldA, int ldB,
    char* ls, int nt, int wid, int lane, f32x4 acc[8][4]) {
  int lr = lane & 15, lg = lane >> 4;
  int wm = wid >> 2, wn = wid & 3;
  int slot16 = (((((lr & 1) << 2) | lg) ^ ((lr >> 1) & 7)) << 4);
  int rdA = wm * 8192 + (lr >> 1) * 128 + slot16;            // + mh*4096 + f*1024
  int rdB = 16384 + wn * 4096 + (lr >> 1) * 128 + slot16;    // + n*1024
  int cc = wid * 2;

#define STG(t, half) do {                                                     \
    char* d_ = ls + ((t) & 3) * 32768 + (half) * 16384 + cc * 1024;           \
    const unsigned short* s_ = ((half) ? pB : pA) + (size_t)(t) * 32;         \
    int ld_ = ((half) ? ldB : ldA);                                           \
    gload16(s_ + (size_t)(cc * 16) * ld_, d_);                                \
    gload16(s_ + (size_t)(cc * 16 + 16) * ld_, d_ + 1024);                    \
  } while (0)

  STG(0, 0); STG(0, 1); STG(1, 0); STG(1, 1); STG(2, 0); STG(2, 1);
  asm volatile("s_waitcnt vmcnt(8)" ::: "memory");   // tile 0 ready
  __builtin_amdgcn_s_barrier();
  __builtin_amdgcn_sched_barrier(0);

  for (int t = 0; t < nt; ++t) {
    char* buf = ls + (t & 3) * 32768;
    bf16x8 aF[4], bF[4];
    // phase 0 (rows wm*128 + 0..63): read B frags + A frags, stage A-half of t+3
#pragma unroll
    for (int n = 0; n < 4; ++n) bF[n] = *(const bf16x8*)(buf + rdB + n * 1024);
#pragma unroll
    for (int f = 0; f < 4; ++f) aF[f] = *(const bf16x8*)(buf + rdA + f * 1024);
    if (t + 3 < nt) STG(t + 3, 0);
    __builtin_amdgcn_s_setprio(1);
#pragma unroll
    for (int f = 0; f < 4; ++f)
#pragma unroll
      for (int n = 0; n < 4; ++n)
        acc[f][n] = __builtin_amdgcn_mfma_f32_16x16x32_bf16(aF[f], bF[n], acc[f][n], 0, 0, 0);
    __builtin_amdgcn_s_setprio(0);
    // phase 1 (rows wm*128 + 64..127): read A frags (B reused), stage B-half of t+3
#pragma unroll
    for (int f = 0; f < 4; ++f) aF[f] = *(const bf16x8*)(buf + rdA + 4096 + f * 1024);
    if (t + 3 < nt) STG(t + 3, 1);
    __builtin_amdgcn_s_setprio(1);
#pragma unroll
    for (int f = 0; f < 4; ++f)
#pragma unroll
      for (int n = 0; n < 4; ++n)
        acc[4 + f][n] = __builtin_amdgcn_mfma_f32_16x16x32_bf16(aF[f], bF[n], acc[4 + f][n], 0, 0, 0);
    __builtin_amdgcn_s_setprio(0);

    if (t == nt - 1) break;
    if (t + 3 < nt)      asm volatile("s_waitcnt vmcnt(8)" ::: "memory");  // t+1 ready
    else if (t + 2 < nt) asm volatile("s_waitcnt vmcnt(4)" ::: "memory");
    else                 asm volatile("s_waitcnt vmcnt(0)" ::: "memory");
    __builtin_amdgcn_s_barrier();
    __builtin_amdgcn_sched_barrier(0);
  }
#undef STG
}

// ---------------- x f32 -> bf16, vectorized
__global__ void convert_x(const float* __restrict__ x, unsigned short* __restrict__ xb) {
  size_t i = ((size_t)blockIdx.x * 256 + threadIdx.x) * 8;
  float4 f0 = *(const float4*)(x + i);
  float4 f1 = *(const float4*)(x + i + 4);
  bf16x8 v;
  v[0] = (short)f2bf(f0.x); v[1] = (short)f2bf(f0.y);
  v[2] = (short)f2bf(f0.z); v[3] = (short)f2bf(f0.w);
  v[4] = (short)f2bf(f1.x); v[5] = (short)f2bf(f1.y);
  v[6] = (short)f2bf(f1.z); v[7] = (short)f2bf(f1.w);
  *(bf16x8*)(xb + i) = v;
}

// ---------------- W transpose+convert: W[768][2304] f32 -> Wt[2304][768] bf16
__global__ void transpose_w(const float* __restrict__ W, unsigned short* __restrict__ Wt) {
  __shared__ float tile[64][65];
  int n0 = (blockIdx.x % 36) * 64;
  int k0 = (blockIdx.x / 36) * 64;
  int tx = threadIdx.x & 63, ty = threadIdx.x >> 6;
#pragma unroll
  for (int p = 0; p < 16; ++p) {
    int k = ty + p * 4;
    tile[k][tx] = W[(size_t)(k0 + k) * ND3 + n0 + tx];
  }
  __syncthreads();
#pragma unroll
  for (int p = 0; p < 16; ++p) {
    int n = ty + p * 4;
    Wt[(size_t)(n0 + n) * DIM + k0 + tx] = f2bf(tile[tx][n]);
  }
}

// ---------------- QKV: xb[16384][768] @ Wt^T -> Q',K',Vt. grid 576 = 64mt x 9nt
__global__ void __launch_bounds__(512, 2) qkv_g8(
    const unsigned short* __restrict__ xb, const unsigned short* __restrict__ Wt,
    const float* __restrict__ bias,
    unsigned short* __restrict__ Qs, unsigned short* __restrict__ Ks,
    unsigned short* __restrict__ Vt) {
  __shared__ char ls[131072];
  int bid = (blockIdx.x & 7) * 72 + (blockIdx.x >> 3);   // bijective XCD swizzle
  int mt = bid / 9, ntb = bid % 9;
  int m0 = mt * 256, n0 = ntb * 256;

  int tid = threadIdx.x, lane = tid & 63, wid = tid >> 6;
  int c8 = (lane & 7) ^ (lane >> 3);
  int rloc = (lane >> 3) * 2 + (c8 >> 2), colo = (c8 & 3) * 8;

  const unsigned short* pA = xb + (size_t)(m0 + rloc) * DIM + colo;
  const unsigned short* pB = Wt + (size_t)(n0 + rloc) * DIM + colo;

  f32x4 acc[8][4] = {};
  gemm256(pA, pB, DIM, DIM, ls, 24, wid, lane, acc);

  int wm = wid >> 2, wn = wid & 3;
  int lr = lane & 15, lg = lane >> 4;
  float bia[4];
#pragma unroll
  for (int n = 0; n < 4; ++n) bia[n] = bias[n0 + wn * 64 + n * 16 + lr];

  if (ntb < 3) {          // Q: * alpha^s / sqrt(d)
#pragma unroll
    for (int f = 0; f < 8; ++f)
#pragma unroll
      for (int r = 0; r < 4; ++r) {
        int mg = m0 + wm * 128 + f * 16 + lg * 4 + r;
        int b = mg >> 10, s = mg & 1023;
        float sc = exp2f((float)s * L2A) * RSQRTD;
        unsigned short* dst = Qs + ((size_t)b * SEQ + s) * DIM + n0 + wn * 64 + lr;
#pragma unroll
        for (int n = 0; n < 4; ++n)
          dst[n * 16] = f2bf((acc[f][n][r] + bia[n]) * sc);
      }
  } else if (ntb < 6) {   // K: * alpha^(-s)
#pragma unroll
    for (int f = 0; f < 8; ++f)
#pragma unroll
      for (int r = 0; r < 4; ++r) {
        int mg = m0 + wm * 128 + f * 16 + lg * 4 + r;
        int b = mg >> 10, s = mg & 1023;
        float sc = exp2f(-(float)s * L2A);
        unsigned short* dst = Ks + ((size_t)b * SEQ + s) * DIM + (n0 - DIM) + wn * 64 + lr;
#pragma unroll
        for (int n = 0; n < 4; ++n)
          dst[n * 16] = f2bf((acc[f][n][r] + bia[n]) * sc);
      }
  } else {                // V: transpose to Vt[b][d][s]
#pragma unroll
    for (int f = 0; f < 8; ++f)
#pragma unroll
      for (int r = 0; r < 4; ++r) {
        int mg = m0 + wm * 128 + f * 16 + lg * 4 + r;
        int b = mg >> 10, s = mg & 1023;
        int d = (n0 - 2 * DIM) + wn * 64 + lr;
        unsigned short* dst = Vt + ((size_t)b * DIM + d) * SEQ + s;
#pragma unroll
        for (int n = 0; n < 4; ++n)
          dst[(size_t)n * 16 * SEQ] = f2bf(acc[f][n][r] + bia[n]);
      }
  }
}

// ---------------- scores: Sm[bl][i][j] = tril(Q' @ K'^T). 10 tril 256^2 tiles/batch
__global__ void __launch_bounds__(512, 2) score_g8(
    const unsigned short* __restrict__ Qs, const unsigned short* __restrict__ Ks,
    unsigned short* __restrict__ Sm, int b_base) {
  __shared__ char ls[131072];
  const signed char IT[10] = {0,1,1,2,2,2,3,3,3,3};
  const signed char JT[10] = {0,0,1,0,1,2,0,1,2,3};
  int bid = (blockIdx.x & 7) * (gridDim.x >> 3) + (blockIdx.x >> 3);
  int t10 = bid % 10, bl = bid / 10;
  int b = b_base + bl;
  int m0 = IT[t10] * 256, n0 = JT[t10] * 256;
  const unsigned short* A  = Qs + (size_t)b * SEQ * DIM;
  const unsigned short* Bt = Ks + (size_t)b * SEQ * DIM;
  unsigned short* Smp = Sm + (size_t)bl * SEQ * SEQ;

  int tid = threadIdx.x, lane = tid & 63, wid = tid >> 6;
  int c8 = (lane & 7) ^ (lane >> 3);
  int rloc = (lane >> 3) * 2 + (c8 >> 2), colo = (c8 & 3) * 8;

  const unsigned short* pA = A  + (size_t)(m0 + rloc) * DIM + colo;
  const unsigned short* pB = Bt + (size_t)(n0 + rloc) * DIM + colo;

  f32x4 acc[8][4] = {};
  gemm256(pA, pB, DIM, DIM, ls, 24, wid, lane, acc);

  int wm = wid >> 2, wn = wid & 3;
  int lr = lane & 15, lg = lane >> 4;
#pragma unroll
  for (int f = 0; f < 8; ++f)
#pragma unroll
    for (int n = 0; n < 4; ++n) {
      int j = n0 + wn * 64 + n * 16 + lr;
#pragma unroll
      for (int r = 0; r < 4; ++r) {
        int i = m0 + wm * 128 + f * 16 + lg * 4 + r;
        float v = acc[f][n][r];
        if (j > i) v = 0.0f;   // causal mask (bites only on diagonal tiles)
        Smp[(size_t)i * SEQ + j] = f2bf(v);
      }
    }
}

// ---------------- PV: out[b][i][d] = Sm[bl] @ V; (i:256, d:256) tiles, heavy-first
__global__ void __launch_bounds__(512, 2) pv_g8(
    const unsigned short* __restrict__ Sm, const unsigned short* __restrict__ Vt,
    float* __restrict__ out, int b_base, int gsz) {
  __shared__ char ls[131072];
  int it = 3 - blockIdx.x / (gsz * 3);     // heavy (large kmax) first
  int rem = blockIdx.x % (gsz * 3);
  int bl = rem / 3, dt = rem % 3;
  int b = b_base + bl;
  int m0 = it * 256, n0 = dt * 256;
  const unsigned short* A  = Sm + (size_t)bl * SEQ * SEQ;   // ld 1024
  const unsigned short* Bt = Vt + (size_t)b * DIM * SEQ;    // ld 1024
  int nt = (it + 1) * 8;                   // K-tiles of 32, causal bound

  int tid = threadIdx.x, lane = tid & 63, wid = tid >> 6;
  int c8 = (lane & 7) ^ (lane >> 3);
  int rloc = (lane >> 3) * 2 + (c8 >> 2), colo = (c8 & 3) * 8;

  const unsigned short* pA = A  + (size_t)(m0 + rloc) * SEQ + colo;
  const unsigned short* pB = Bt + (size_t)(n0 + rloc) * SEQ + colo;

  f32x4 acc[8][4] = {};
  gemm256(pA, pB, SEQ, SEQ, ls, nt, wid, lane, acc);

  int wm = wid >> 2, wn = wid & 3;
  int lr = lane & 15, lg = lane >> 4;
#pragma unroll
  for (int f = 0; f < 8; ++f)
#pragma unroll
    for (int n = 0; n < 4; ++n) {
      int d = n0 + wn * 64 + n * 16 + lr;
#pragma unroll
      for (int r = 0; r < 4; ++r) {
        int i = m0 + wm * 128 + f * 16 + lg * 4 + r;
        out[((size_t)b * SEQ + i) * DIM + d] = acc[f][n][r];
      }
    }
}

extern "C" void kernel_launch(void* const* d_in, const int* in_sizes, int n_in,
                              void* d_out, int out_size, void* d_ws, size_t ws_size,
                              hipStream_t stream) {
  const float* x    = (const float*)d_in[0];
  const float* W    = (const float*)d_in[1];
  const float* bias = (const float*)d_in[2];
  float* out = (float*)d_out;

  char* ws = (char*)d_ws;
  // ws: Wt 3.5MB | Qs/Ks/Vt 25.2MB each | Sm 16.8MB (8 batches) or 33.6MB (16)
  unsigned short* Wt = (unsigned short*)(ws);
  unsigned short* Qs = (unsigned short*)(ws + 3538944);
  unsigned short* Ks = (unsigned short*)(ws + 3538944 + 25165824);
  unsigned short* Vt = (unsigned short*)(ws + 3538944 + 2 * 25165824);
  unsigned short* Sm = (unsigned short*)(ws + 3538944 + 3 * 25165824);
  // bf16 x lives in d_out (50.3MB >= 25.2MB); fully consumed by qkv before pv writes.
  unsigned short* xb = (unsigned short*)d_out;

  size_t smBase = 3538944 + 3 * (size_t)25165824;
  int gsz = (ws_size >= smBase + (size_t)16 * SEQ * SEQ * 2) ? 16 : 8;
  int ngrp = 16 / gsz;

  transpose_w<<<36 * 12, 256, 0, stream>>>(W, Wt);
  convert_x<<<6144, 256, 0, stream>>>(x, xb);
  qkv_g8<<<576, 512, 0, stream>>>(xb, Wt, bias, Qs, Ks, Vt);
  for (int g = 0; g < ngrp; ++g) {
    score_g8<<<gsz * 10, 512, 0, stream>>>(Qs, Ks, Sm, g * gsz);
    pv_g8<<<gsz * 12, 512, 0, stream>>>(Sm, Vt, out, g * gsz, gsz);
  }
}

// Round 7
// 155.695 us; speedup vs baseline: 1.0087x; 1.0087x over previous
//
#include <hip/hip_runtime.h>
#include <hip/hip_bf16.h>

// Retention: out = (tril(alpha^(i-j)) * (QK^T/sqrt(d))) @ V, qkv = x@W + b
// Decay folded into operands: Q' = q*alpha^i/sqrt(d), K' = k*alpha^(-j)
// qkv: 256x256, BK=64, 8 waves, m201-style 8-phase schedule:
//   per phase { ds_read frags ; stage half-tiles ; barrier ; MFMA x16 ; [gate] ; barrier }
//   gates = counted vmcnt(4) at phases 3 and 7 only (never drain mid-loop).
// score/pv: r5 structure (128x128, BK=64 dbuf, counted vmcnt(4), 0 conflicts measured).

#define SEQ   1024
#define DIM   768
#define ND3   2304

typedef __attribute__((ext_vector_type(8))) short bf16x8;
typedef __attribute__((ext_vector_type(4))) float f32x4;

#define L2A     (-0.014499569695115089f)   // log2(0.99)
#define RSQRTD  (0.03608439182435161f)     // 1/sqrt(768)

__device__ __forceinline__ unsigned short f2bf(float x) {
  union { float f; unsigned u; } v; v.f = x;
  unsigned r = v.u + 0x7FFFu + ((v.u >> 16) & 1u);
  return (unsigned short)(r >> 16);
}

__device__ __forceinline__ void gload16(const void* g, void* l) {
  __builtin_amdgcn_global_load_lds(
      (const __attribute__((address_space(1))) void*)g,
      (__attribute__((address_space(3))) void*)l, 16, 0, 0);
}

// ======================= QKV: 256^2 8-phase =======================
// LDS 128KB: A at ls[0..64K): [buf][half(128rows)][row][8 slots x16B]
//            B at ls[64K..128K): same.
// slot swizzle: slot = (ks*4+lg) ^ (lr&7); staged via pre-swizzled global col
// cs = ((lane&7)^(lane>>3))*8 with linear LDS dest (rule: both-sides-or-neither).
//
// Race-freedom:
//  - slot freed: A(buf0) last ds_read in ph3 (completed before ph3 end-barrier,
//    reads are data-dependence-waited before MFMA which precedes the barrier);
//    B(buf0) last read ph2; A(buf1) ph7; B(buf1) ph6.
//  - stage issue points: A(kt1)->buf1 @ph0 (after prev ph7 barrier), B(kt2)->buf0
//    @ph3 (after ph2 barrier), A(kt2)->buf0 @ph4 (after ph3 barrier),
//    B(kt3)->buf1 @ph7 (after ph6 barrier). All >= free point.
//  - gate end-ph3: queue = [B(kt1)(4, prev ph7), A(kt1)(4, ph0), B(kt2)(4, ph3)]
//    -> vmcnt(4) completes kt1 before ph4 reads it. Symmetric at end-ph7.

__global__ void __launch_bounds__(512, 2) qkv_g8(
    const unsigned short* __restrict__ xb, const unsigned short* __restrict__ Wt,
    const float* __restrict__ bias,
    unsigned short* __restrict__ Qs, unsigned short* __restrict__ Ks,
    unsigned short* __restrict__ Vt) {
  __shared__ __align__(1024) char ls[131072];
  char* lsA = ls;
  char* lsB = ls + 65536;

  int bid = (blockIdx.x & 7) * 72 + (blockIdx.x >> 3);   // bijective XCD swizzle
  int mt = bid / 9, ntb = bid % 9;
  int m0 = mt * 256, n0 = ntb * 256;

  int tid = threadIdx.x, lane = tid & 63, wid = tid >> 6;
  int wm = wid >> 2, wn = wid & 3;            // 2M x 4N waves, per-wave 128x64
  int lr = lane & 15, lg = lane >> 4;
  int l8 = lane >> 3, cs = ((lane & 7) ^ l8) << 3;

  const unsigned short* pA = xb + (size_t)(m0 + l8) * DIM + cs;
  const unsigned short* pB = Wt + (size_t)(n0 + l8) * DIM + cs;

  int rdA = wm * 16384 + lr * 128 + ((lg ^ (lr & 7)) << 4);
  int rdB = (wn >> 1) * 16384 + (wn & 1) * 8192 + lr * 128 + ((lg ^ (lr & 7)) << 4);

#define STG_A(kt, h) do {                                                      \
    gload16(pA + (size_t)((h) * 128 + wid * 16) * DIM + (kt) * 64,             \
            lsA + (((kt) & 1) << 15) + ((h) << 14) + wid * 2048);              \
    gload16(pA + (size_t)((h) * 128 + wid * 16 + 8) * DIM + (kt) * 64,         \
            lsA + (((kt) & 1) << 15) + ((h) << 14) + wid * 2048 + 1024);       \
  } while (0)
#define STG_B(kt, h) do {                                                      \
    gload16(pB + (size_t)((h) * 128 + wid * 16) * DIM + (kt) * 64,             \
            lsB + (((kt) & 1) << 15) + ((h) << 14) + wid * 2048);              \
    gload16(pB + (size_t)((h) * 128 + wid * 16 + 8) * DIM + (kt) * 64,         \
            lsB + (((kt) & 1) << 15) + ((h) << 14) + wid * 2048 + 1024);       \
  } while (0)
#define LD_A(kt, mh, ks) do {                                                  \
    _Pragma("unroll")                                                          \
    for (int f = 0; f < 4; ++f)                                                \
      aF[f] = *(const bf16x8*)(lsA + (((kt) & 1) << 15) +                      \
              ((rdA + (mh) * 8192 + f * 2048) ^ ((ks) << 6)));                 \
  } while (0)
#define LD_B(kt, ks) do {                                                      \
    _Pragma("unroll")                                                          \
    for (int n = 0; n < 4; ++n)                                                \
      bF[n] = *(const bf16x8*)(lsB + (((kt) & 1) << 15) +                      \
              ((rdB + n * 2048) ^ ((ks) << 6)));                               \
  } while (0)
#define MFMA16(mh) do {                                                        \
    __builtin_amdgcn_s_setprio(1);                                             \
    _Pragma("unroll")                                                          \
    for (int f = 0; f < 4; ++f)                                                \
      _Pragma("unroll")                                                        \
      for (int n = 0; n < 4; ++n)                                              \
        acc[(mh) * 4 + f][n] = __builtin_amdgcn_mfma_f32_16x16x32_bf16(        \
            aF[f], bF[n], acc[(mh) * 4 + f][n], 0, 0, 0);                      \
    __builtin_amdgcn_s_setprio(0);                                             \
  } while (0)
#define BAR do { asm volatile("" ::: "memory");                                \
    __builtin_amdgcn_s_barrier(); asm volatile("" ::: "memory"); } while (0)
#define GATE(n) asm volatile("s_waitcnt vmcnt(" #n ")" ::: "memory")

  f32x4 acc[8][4] = {};
  bf16x8 aF[4], bF[4];

  // prologue: kt0 fully + B(kt1)  (issue order defines the FIFO)
  STG_B(0, 0); STG_B(0, 1); STG_A(0, 0); STG_A(0, 1);
  STG_B(1, 0); STG_B(1, 1);
  GATE(4);          // kt0 complete, B(kt1) in flight
  BAR;

  for (int t = 0; t < 6; ++t) {
    const int kt0 = 2 * t, kt1 = 2 * t + 1, kt2 = 2 * t + 2, kt3 = 2 * t + 3;
    // ph0: buf0 (mh0,ks0); stage A(kt1)
    LD_B(kt0, 0); LD_A(kt0, 0, 0);
    STG_A(kt1, 0); STG_A(kt1, 1);
    BAR; MFMA16(0); BAR;
    // ph1: buf0 (mh1,ks0)
    LD_A(kt0, 1, 0);
    BAR; MFMA16(1); BAR;
    // ph2: buf0 (mh0,ks1)
    LD_B(kt0, 1); LD_A(kt0, 0, 1);
    BAR; MFMA16(0); BAR;
    // ph3: buf0 (mh1,ks1); stage B(kt2); gate kt1
    LD_A(kt0, 1, 1);
    if (t < 5) { STG_B(kt2, 0); STG_B(kt2, 1); }
    BAR; MFMA16(1);
    if (t < 5) GATE(4); else GATE(0);
    BAR;
    // ph4: buf1 (mh0,ks0); stage A(kt2)
    LD_B(kt1, 0); LD_A(kt1, 0, 0);
    if (t < 5) { STG_A(kt2, 0); STG_A(kt2, 1); }
    BAR; MFMA16(0); BAR;
    // ph5: buf1 (mh1,ks0)
    LD_A(kt1, 1, 0);
    BAR; MFMA16(1); BAR;
    // ph6: buf1 (mh0,ks1)
    LD_B(kt1, 1); LD_A(kt1, 0, 1);
    BAR; MFMA16(0); BAR;
    // ph7: buf1 (mh1,ks1); stage B(kt3); gate kt2
    LD_A(kt1, 1, 1);
    if (t < 5) { STG_B(kt3, 0); STG_B(kt3, 1); }
    BAR; MFMA16(1);
    if (t < 5) { GATE(4); BAR; }
  }
#undef STG_A
#undef STG_B
#undef LD_A
#undef LD_B
#undef MFMA16
#undef BAR
#undef GATE

  // epilogue: bias + decay; ntb<3 -> Q, <6 -> K, else V (exact 256-col splits)
  float bia[4];
#pragma unroll
  for (int n = 0; n < 4; ++n) bia[n] = bias[n0 + wn * 64 + n * 16 + lr];

  if (ntb < 3) {          // Q: * alpha^s / sqrt(d)
#pragma unroll
    for (int f = 0; f < 8; ++f)
#pragma unroll
      for (int r = 0; r < 4; ++r) {
        int mg = m0 + wm * 128 + f * 16 + lg * 4 + r;
        int b = mg >> 10, s = mg & 1023;
        float sc = exp2f((float)s * L2A) * RSQRTD;
        unsigned short* dst = Qs + ((size_t)b * SEQ + s) * DIM + n0 + wn * 64 + lr;
#pragma unroll
        for (int n = 0; n < 4; ++n)
          dst[n * 16] = f2bf((acc[f][n][r] + bia[n]) * sc);
      }
  } else if (ntb < 6) {   // K: * alpha^(-s)
#pragma unroll
    for (int f = 0; f < 8; ++f)
#pragma unroll
      for (int r = 0; r < 4; ++r) {
        int mg = m0 + wm * 128 + f * 16 + lg * 4 + r;
        int b = mg >> 10, s = mg & 1023;
        float sc = exp2f(-(float)s * L2A);
        unsigned short* dst = Ks + ((size_t)b * SEQ + s) * DIM + (n0 - DIM) + wn * 64 + lr;
#pragma unroll
        for (int n = 0; n < 4; ++n)
          dst[n * 16] = f2bf((acc[f][n][r] + bia[n]) * sc);
      }
  } else {                // V: transpose to Vt[b][d][s]
#pragma unroll
    for (int f = 0; f < 8; ++f)
#pragma unroll
      for (int r = 0; r < 4; ++r) {
        int mg = m0 + wm * 128 + f * 16 + lg * 4 + r;
        int b = mg >> 10, s = mg & 1023;
        int d = (n0 - 2 * DIM) + wn * 64 + lr;
        unsigned short* dst = Vt + ((size_t)b * DIM + d) * SEQ + s;
#pragma unroll
        for (int n = 0; n < 4; ++n)
          dst[(size_t)n * 16 * SEQ] = f2bf(acc[f][n][r] + bia[n]);
      }
  }
}

// ======================= r5 pieces (unchanged, proven) =======================

__device__ __forceinline__ void gemm_core(
    const unsigned short* gA, const unsigned short* gA2,
    const unsigned short* gB, const unsigned short* gB2,
    char* lsA, char* lsB, int nt, int wid, int lane, f32x4 acc[2][4]) {
  int lr = lane & 15, lg = lane >> 4;
  int wm = wid >> 1, wn = wid & 1;
  int rdA = (wm * 32 + lr) * 128 + ((lg ^ (lr & 7)) << 4);
  int rdB = (wn * 64 + lr) * 128 + ((lg ^ (lr & 7)) << 4);
  int wo = wid * 2048;

#define STAGE(t, par) do {                                                    \
    int lo_ = ((par) << 14) + wo;                                             \
    gload16(gA  + (size_t)(t) * 64, lsA + lo_);                               \
    gload16(gA2 + (size_t)(t) * 64, lsA + lo_ + 1024);                        \
    gload16(gB  + (size_t)(t) * 64, lsB + lo_);                               \
    gload16(gB2 + (size_t)(t) * 64, lsB + lo_ + 1024);                        \
  } while (0)

  STAGE(0, 0);
  STAGE(1, 1);
  asm volatile("s_waitcnt vmcnt(4)" ::: "memory");   // tile 0 ready
  __builtin_amdgcn_s_barrier();
  asm volatile("" ::: "memory");

  for (int t = 0; t < nt; ++t) {
    int pbase = (t & 1) << 14;
    bf16x8 aF[2][2], bF[2][4];
#pragma unroll
    for (int kh = 0; kh < 2; ++kh) {
#pragma unroll
      for (int f = 0; f < 2; ++f)
        aF[kh][f] = *(const bf16x8*)(lsA + pbase + ((rdA + f * 2048) ^ (kh << 6)));
#pragma unroll
      for (int n = 0; n < 4; ++n)
        bF[kh][n] = *(const bf16x8*)(lsB + pbase + ((rdB + n * 2048) ^ (kh << 6)));
    }
    __builtin_amdgcn_s_setprio(1);
#pragma unroll
    for (int kh = 0; kh < 2; ++kh)
#pragma unroll
      for (int f = 0; f < 2; ++f)
#pragma unroll
        for (int n = 0; n < 4; ++n)
          acc[f][n] = __builtin_amdgcn_mfma_f32_16x16x32_bf16(aF[kh][f], bF[kh][n], acc[f][n], 0, 0, 0);
    __builtin_amdgcn_s_setprio(0);

    if (t == nt - 1) break;
    __builtin_amdgcn_s_barrier();
    asm volatile("" ::: "memory");
    if (t + 2 < nt) {
      STAGE(t + 2, t & 1);
      asm volatile("s_waitcnt vmcnt(4)" ::: "memory");
    } else {
      asm volatile("s_waitcnt vmcnt(0)" ::: "memory");
    }
    __builtin_amdgcn_s_barrier();
    asm volatile("" ::: "memory");
  }
#undef STAGE
}

__global__ void convert_x(const float* __restrict__ x, unsigned short* __restrict__ xb) {
  size_t i = ((size_t)blockIdx.x * 256 + threadIdx.x) * 8;
  float4 f0 = *(const float4*)(x + i);
  float4 f1 = *(const float4*)(x + i + 4);
  bf16x8 v;
  v[0] = (short)f2bf(f0.x); v[1] = (short)f2bf(f0.y);
  v[2] = (short)f2bf(f0.z); v[3] = (short)f2bf(f0.w);
  v[4] = (short)f2bf(f1.x); v[5] = (short)f2bf(f1.y);
  v[6] = (short)f2bf(f1.z); v[7] = (short)f2bf(f1.w);
  *(bf16x8*)(xb + i) = v;
}

__global__ void transpose_w(const float* __restrict__ W, unsigned short* __restrict__ Wt) {
  __shared__ float tile[64][65];
  int n0 = (blockIdx.x % 36) * 64;
  int k0 = (blockIdx.x / 36) * 64;
  int tx = threadIdx.x & 63, ty = threadIdx.x >> 6;
#pragma unroll
  for (int p = 0; p < 16; ++p) {
    int k = ty + p * 4;
    tile[k][tx] = W[(size_t)(k0 + k) * ND3 + n0 + tx];
  }
  __syncthreads();
#pragma unroll
  for (int p = 0; p < 16; ++p) {
    int n = ty + p * 4;
    Wt[(size_t)(n0 + n) * DIM + k0 + tx] = f2bf(tile[tx][n]);
  }
}

// scores: Sm[bl][i][j] = tril(Q' @ K'^T). 36 lower-tri 128x128 tiles/batch
__global__ void __launch_bounds__(512, 4) score_g(
    const unsigned short* __restrict__ Qs, const unsigned short* __restrict__ Ks,
    unsigned short* __restrict__ Sm, int b_base) {
  __shared__ __align__(1024) char lsA[32768];
  __shared__ __align__(1024) char lsB[32768];
  int bid = (blockIdx.x & 7) * (gridDim.x >> 3) + (blockIdx.x >> 3);
  int t = bid % 36, bl = bid / 36;
  int b = b_base + bl;
  int it = 0;
  while (t >= it + 1) { t -= it + 1; it++; }
  int jt = t;
  int m0 = it * 128, n0 = jt * 128;
  const unsigned short* A  = Qs + (size_t)b * SEQ * DIM;
  const unsigned short* Bt = Ks + (size_t)b * SEQ * DIM;
  unsigned short* Smp = Sm + (size_t)bl * SEQ * SEQ;

  int tid = threadIdx.x, lane = tid & 63, wid = tid >> 6;
  int l8 = lane >> 3, cs = ((lane & 7) ^ l8) << 3;
  int srow = wid * 16 + l8;

  const unsigned short* gA = A  + (size_t)(m0 + srow) * DIM + cs;
  const unsigned short* gB = Bt + (size_t)(n0 + srow) * DIM + cs;

  f32x4 acc[2][4] = {};
  gemm_core(gA, gA + 8 * DIM, gB, gB + 8 * DIM, lsA, lsB, 12, wid, lane, acc);

  int wm = wid >> 1, wn = wid & 1;
  int lr = lane & 15, lg = lane >> 4;
#pragma unroll
  for (int f = 0; f < 2; ++f)
#pragma unroll
    for (int n = 0; n < 4; ++n) {
      int j = n0 + wn * 64 + n * 16 + lr;
#pragma unroll
      for (int r = 0; r < 4; ++r) {
        int i = m0 + wm * 32 + f * 16 + lg * 4 + r;
        float v = acc[f][n][r];
        if (j > i) v = 0.0f;   // causal mask (bites only on diagonal tiles)
        Smp[(size_t)i * SEQ + j] = f2bf(v);
      }
    }
}

// PV: out[b][i][d] = Sm[bl] @ V; tiles (i:128, d:128), heavy-first
__global__ void __launch_bounds__(512, 4) pv_g(
    const unsigned short* __restrict__ Sm, const unsigned short* __restrict__ Vt,
    float* __restrict__ out, int b_base, int gsz) {
  __shared__ __align__(1024) char lsA[32768];
  __shared__ __align__(1024) char lsB[32768];
  int it = 7 - blockIdx.x / (gsz * 6);     // heavy (large kmax) first
  int rem = blockIdx.x % (gsz * 6);
  int bl = rem / 6, dt = rem % 6;
  int b = b_base + bl;
  int m0 = it * 128, n0 = dt * 128;
  const unsigned short* A  = Sm + (size_t)bl * SEQ * SEQ;
  const unsigned short* Bt = Vt + (size_t)b * DIM * SEQ;
  int nt = (it + 1) * 2;

  int tid = threadIdx.x, lane = tid & 63, wid = tid >> 6;
  int l8 = lane >> 3, cs = ((lane & 7) ^ l8) << 3;
  int srow = wid * 16 + l8;

  const unsigned short* gA = A  + (size_t)(m0 + srow) * SEQ + cs;
  const unsigned short* gB = Bt + (size_t)(n0 + srow) * SEQ + cs;

  f32x4 acc[2][4] = {};
  gemm_core(gA, gA + 8 * SEQ, gB, gB + 8 * SEQ, lsA, lsB, nt, wid, lane, acc);

  int wm = wid >> 1, wn = wid & 1;
  int lr = lane & 15, lg = lane >> 4;
#pragma unroll
  for (int f = 0; f < 2; ++f)
#pragma unroll
    for (int n = 0; n < 4; ++n) {
      int d = n0 + wn * 64 + n * 16 + lr;
#pragma unroll
      for (int r = 0; r < 4; ++r) {
        int i = m0 + wm * 32 + f * 16 + lg * 4 + r;
        out[((size_t)b * SEQ + i) * DIM + d] = acc[f][n][r];
      }
    }
}

extern "C" void kernel_launch(void* const* d_in, const int* in_sizes, int n_in,
                              void* d_out, int out_size, void* d_ws, size_t ws_size,
                              hipStream_t stream) {
  const float* x    = (const float*)d_in[0];
  const float* W    = (const float*)d_in[1];
  const float* bias = (const float*)d_in[2];
  float* out = (float*)d_out;

  char* ws = (char*)d_ws;
  // ws: Wt 3.5MB | Qs/Ks/Vt 25.2MB each | Sm 16.8MB (8 batches) or 33.6MB (16)
  unsigned short* Wt = (unsigned short*)(ws);
  unsigned short* Qs = (unsigned short*)(ws + 3538944);
  unsigned short* Ks = (unsigned short*)(ws + 3538944 + 25165824);
  unsigned short* Vt = (unsigned short*)(ws + 3538944 + 2 * 25165824);
  unsigned short* Sm = (unsigned short*)(ws + 3538944 + 3 * 25165824);
  // bf16 x lives in d_out (50.3MB >= 25.2MB); fully consumed by qkv before pv writes.
  unsigned short* xb = (unsigned short*)d_out;

  size_t smBase = 3538944 + 3 * (size_t)25165824;
  int gsz = (ws_size >= smBase + (size_t)16 * SEQ * SEQ * 2) ? 16 : 8;
  int ngrp = 16 / gsz;

  transpose_w<<<36 * 12, 256, 0, stream>>>(W, Wt);
  convert_x<<<6144, 256, 0, stream>>>(x, xb);
  qkv_g8<<<576, 512, 0, stream>>>(xb, Wt, bias, Qs, Ks, Vt);
  for (int g = 0; g < ngrp; ++g) {
    score_g<<<gsz * 36, 512, 0, stream>>>(Qs, Ks, Sm, g * gsz);
    pv_g<<<gsz * 48, 512, 0, stream>>>(Sm, Vt, out, g * gsz, gsz);
  }
}